// Round 5
// baseline (163.099 us; speedup 1.0000x reference)
//
#include <hip/hip_runtime.h>
#include <math.h>

#define B_    4
#define C_    19
#define H_    320
#define W_    320
#define HW_   (H_*W_)
#define CHW_  (C_*HW_)
#define NPIX_ (B_*HW_)
#define NEPS_ 256
#define BIGI_ (1<<20)
#define INF_  0x3fffffff
#define IGN_  255
#define FUSED_BLKS_ 320   /* NPIX_/(320 threads * 4 px) */

// Compile-time exact replica of the reference eps chain: e0=1e-5f, e_{k+1}=e_k*1.2f
// (constexpr fp32 multiply uses IEEE RNE — identical to runtime sequence).
struct EpsTab { float v[NEPS_]; };
static constexpr EpsTab make_eps() {
  EpsTab t{}; float e = 1e-5f;
  for (int k = 0; k < NEPS_; ++k) { t.v[k] = e; e = e * 1.2f; }
  return t;
}
__device__ __constant__ EpsTab EPS = make_eps();

// ---------------- reduction helper (nw waves, full waves only) --------------
__device__ __forceinline__ void block_reduce_add_w(float v, float* out, int nw) {
  #pragma unroll
  for (int o = 32; o > 0; o >>= 1) v += __shfl_down(v, o);
  __shared__ float shr[8];
  int lane = threadIdx.x & 63, wid = threadIdx.x >> 6;
  if (lane == 0) shr[wid] = v;
  __syncthreads();
  if (threadIdx.x == 0) {
    float s = 0.f;
    for (int w = 0; w < nw; ++w) s += shr[w];
    atomicAdd(out, s);
  }
}

// ---------------- K1: fused softmax/kl/hist/nll (blocks 0..319)  ------------
//                     row-DT scan              (blocks 320..1599) ------------
__global__ __launch_bounds__(320) void k_front(const float* __restrict__ sl, const int* __restrict__ tgt,
                                               int* __restrict__ R, float* __restrict__ logZ,
                                               float* __restrict__ S, float* __restrict__ kl_map,
                                               int* __restrict__ hist, float* __restrict__ out) {
  int tid = threadIdx.x;
  if (blockIdx.x < FUSED_BLKS_) {
    // ---- fused: 4 px per thread, float4 loads, no-max softmax ----
    __shared__ float et[NEPS_];
    __shared__ int sh[257];
    for (int e = tid; e < 257; e += 320) sh[e] = 0;
    for (int e = tid; e < NEPS_; e += 320) et[e] = EPS.v[e];
    __syncthreads();
    int flat0 = blockIdx.x * 1280 + tid * 4;
    int b = flat0 / HW_, pix = flat0 - b * HW_;
    int i = pix / W_, j = pix - i * W_;
    const float* base = sl + (size_t)b * CHW_ + pix;
    bool hd = (i < H_ - 1);          // down neighbor exists
    bool hn = (j < W_ - 4);          // 5th column (right nbr of p=3) exists
    float se[4] = {0,0,0,0}, E[4] = {0,0,0,0}, sed[4] = {0,0,0,0}, sen = 0.f;
    #pragma unroll
    for (int c = 0; c < C_; ++c) {
      const float* pc = base + c * HW_;
      float4 xs = *(const float4*)pc;
      float e0 = __expf(xs.x), e1 = __expf(xs.y), e2 = __expf(xs.z), e3 = __expf(xs.w);
      se[0] += e0; se[1] += e1; se[2] += e2; se[3] += e3;
      E[0] += e0 * xs.x; E[1] += e1 * xs.y; E[2] += e2 * xs.z; E[3] += e3 * xs.w;
      if (hd) {
        float4 xd = *(const float4*)(pc + W_);
        sed[0] += __expf(xd.x); sed[1] += __expf(xd.y); sed[2] += __expf(xd.z); sed[3] += __expf(xd.w);
      }
      if (hn) sen += __expf(pc[4]);
    }
    float lz[4], Sv[4], lzd[4] = {0,0,0,0}, lzn = 0.f;
    #pragma unroll
    for (int p = 0; p < 4; ++p) { lz[p] = __logf(se[p]); Sv[p] = E[p] / se[p] - lz[p]; }
    if (hd) {
      #pragma unroll
      for (int p = 0; p < 4; ++p) lzd[p] = __logf(sed[p]);
    }
    if (hn) lzn = __logf(sen);
    // target nll
    int4 tv = *(const int4*)(tgt + flat0);
    float nll = 0.f;
    if (tv.x != IGN_) nll += lz[0] - base[tv.x * HW_ + 0];
    if (tv.y != IGN_) nll += lz[1] - base[tv.y * HW_ + 1];
    if (tv.z != IGN_) nll += lz[2] - base[tv.z * HW_ + 2];
    if (tv.w != IGN_) nll += lz[3] - base[tv.w * HW_ + 3];
    // pass 2: dots (L1-hot reloads)
    float dotd[4] = {0,0,0,0}, dotr[4] = {0,0,0,0};
    #pragma unroll
    for (int c = 0; c < C_; ++c) {
      const float* pc = base + c * HW_;
      float4 xs = *(const float4*)pc;
      float p0 = __expf(xs.x - lz[0]), p1 = __expf(xs.y - lz[1]);
      float p2 = __expf(xs.z - lz[2]), p3 = __expf(xs.w - lz[3]);
      if (hd) {
        float4 xd = *(const float4*)(pc + W_);
        dotd[0] += p0 * xd.x; dotd[1] += p1 * xd.y; dotd[2] += p2 * xd.z; dotd[3] += p3 * xd.w;
      }
      dotr[0] += p0 * xs.y; dotr[1] += p1 * xs.z; dotr[2] += p2 * xs.w;
      if (hn) dotr[3] += p3 * pc[4];
    }
    float kl4[4];
    #pragma unroll
    for (int p = 0; p < 4; ++p) {
      float kl = 0.f;
      if (hd) kl += Sv[p] - dotd[p] + lzd[p];
      bool hr = (p < 3) || hn;
      if (hr) {
        float lzr = (p < 3) ? lz[p + 1] : lzn;
        kl += Sv[p] - dotr[p] + lzr;
      }
      kl4[p] = kl;
      // bin = #{k : e_k < kl}; log2-guess + exact correction against et[]
      int g;
      if (!(kl > 1e-5f)) g = 0;
      else {
        g = (int)((__log2f(kl) + 16.6096404f) * 3.8017840f);
        g = min(max(g, 0), NEPS_ - 1);
        while (g < NEPS_ && et[g] < kl) ++g;
        while (g > 0 && !(et[g - 1] < kl)) --g;
      }
      atomicAdd(&sh[g], 1);
    }
    *(float4*)(logZ + flat0)   = make_float4(lz[0], lz[1], lz[2], lz[3]);
    *(float4*)(S + flat0)      = make_float4(Sv[0], Sv[1], Sv[2], Sv[3]);
    *(float4*)(kl_map + flat0) = make_float4(kl4[0], kl4[1], kl4[2], kl4[3]);
    __syncthreads();
    for (int e = tid; e < 257; e += 320)
      if (sh[e]) atomicAdd(&hist[e], sh[e]);
    block_reduce_add_w(nll, out, 5);
  } else {
    // ---- row-wise 1D seed distance (Hillis-Steele min scans) ----
    int bid = blockIdx.x - FUSED_BLKS_;
    int b = bid / H_, i = bid % H_, j = tid;
    const int* t = tgt + b * HW_;
    int tij = t[i * W_ + j];
    bool bnd = (tij == IGN_);
    if (i < H_ - 1) bnd |= (t[(i + 1) * W_ + j] != tij);
    if (j < W_ - 1) bnd |= (t[i * W_ + j + 1] != tij);
    int s = bnd ? 0 : BIGI_;
    __shared__ int a[W_], c[W_];
    a[j] = s - j; c[j] = s + j;
    for (int ofs = 1; ofs < W_; ofs <<= 1) {
      __syncthreads();
      int av = (j >= ofs)     ? a[j - ofs] : INF_;
      int cv = (j + ofs < W_) ? c[j + ofs] : INF_;
      __syncthreads();
      a[j] = min(a[j], av); c[j] = min(c[j], cv);
    }
    R[(b * H_ + i) * W_ + j] = min(a[j] + j, c[j] - j);
  }
}

// ---------------- K2: column combine dist = min_i max(|i-i0|, R_i) ----------
__global__ __launch_bounds__(H_) void k_coldt(const int* __restrict__ R, int* __restrict__ dist) {
  int b = blockIdx.x / W_, j = blockIdx.x % W_, tid = threadIdx.x;
  __shared__ int lev[9][H_];
  lev[0][tid] = R[(b * H_ + tid) * W_ + j];
  int Ri = lev[0][tid];
  for (int l = 1; l <= 8; ++l) {
    int half = 1 << (l - 1);
    __syncthreads();
    int other = (tid + half < H_) ? lev[l - 1][tid + half] : INF_;
    lev[l][tid] = min(lev[l - 1][tid], other);
  }
  __syncthreads();
  int i0 = tid;
  auto feas = [&](int dd) -> bool {
    int lo = max(0, i0 - dd), hi = min(H_ - 1, i0 + dd);
    int len = hi - lo + 1;
    int l = 31 - __clz(len);
    int m = min(lev[l][lo], lev[l][hi - (1 << l) + 1]);
    return m <= dd;
  };
  int d;
  int hi = min(Ri, 512);         // d <= R[i0] (take i=i0)
  if (!feas(hi)) d = B_ + 1 + H_ + W_;   // only reachable when no seed in image
  else {
    int lo = 0;
    while (lo < hi) { int mid = (lo + hi) >> 1; if (feas(mid)) hi = mid; else lo = mid + 1; }
    d = lo;
  }
  dist[(b * H_ + i0) * W_ + j] = d;
}

// ---------------- K3: mask+direction+dterm + in-block sparse CE -------------
__global__ __launch_bounds__(256) void k_maskce(const float* __restrict__ sl, const float* __restrict__ logZ,
                                                const float* __restrict__ S, const float* __restrict__ kl_map,
                                                const int* __restrict__ dist, const int* __restrict__ hist,
                                                float* __restrict__ out) {
  const int nx9[9] = {1,-1,0,0,-1,1,-1,1,0};
  const int ny9[9] = {0,0,-1,1,1,1,-1,-1,0};
  int tid = threadIdx.x;
  int b = blockIdx.z;
  int i0 = blockIdx.y * 16, j0 = blockIdx.x * 16;
  // eps via suffix scan of hist (bins 1..256)
  __shared__ int g[256];
  __shared__ int bestk;
  g[tid] = hist[tid + 1];
  if (tid == 0) bestk = NEPS_ - 1;
  __syncthreads();
  #pragma unroll
  for (int ofs = 1; ofs < 256; ofs <<= 1) {
    int v = g[tid] + ((tid + ofs < 256) ? g[tid + ofs] : 0);
    __syncthreads();
    g[tid] = v;
    __syncthreads();
  }
  if (g[tid] <= 5120) atomicMin(&bestk, tid);
  __syncthreads();
  float eps = EPS.v[bestk];
  // tile + halo
  __shared__ float kt[18][19];
  __shared__ int   dt_[18][19];
  for (int e = tid; e < 324; e += 256) {
    int r = e / 18, cc = e - r * 18;
    int gi = i0 - 1 + r, gj = j0 - 1 + cc;
    bool in = (gi >= 0 && gi < H_ && gj >= 0 && gj < W_);
    int gidx = (b * H_ + gi) * W_ + gj;
    kt[r][cc]  = in ? kl_map[gidx] : -1e30f;
    dt_[r][cc] = in ? dist[gidx] : 100000;
  }
  __syncthreads();
  int li = tid >> 4, lj = tid & 15;
  bool mask = false;
  #pragma unroll
  for (int dr = 0; dr < 3; ++dr)
    #pragma unroll
    for (int dc = 0; dc < 3; ++dc)
      mask |= (kt[li + dr][lj + dc] > eps);
  int best = INF_, dir = 0;
  #pragma unroll
  for (int k = 0; k < 9; ++k) {
    int r = dt_[li + 1 + nx9[k]][lj + 1 + ny9[k]];
    if (r < best) { best = r; dir = k; }
  }
  bool valid = mask && (dir != 8);
  float acc = valid ? fminf((float)dt_[li + 1][lj + 1], 20.f) * (1.f / 20.f) : 0.f;
  // compact valid pixels into LDS list
  __shared__ int list_[256];
  __shared__ int woff[4];
  __shared__ int tot_s;
  int lane = tid & 63, wid = tid >> 6;
  unsigned long long vote = __ballot(valid);
  if (lane == 0) woff[wid] = __popcll(vote);
  __syncthreads();
  if (tid == 0) {
    int c0 = woff[0], c1 = woff[1], c2 = woff[2], c3 = woff[3];
    tot_s = c0 + c1 + c2 + c3;
    woff[0] = 0; woff[1] = c0; woff[2] = c0 + c1; woff[3] = c0 + c1 + c2;
  }
  __syncthreads();
  if (valid)
    list_[woff[wid] + __popcll(vote & ((1ULL << lane) - 1ULL))] = tid | (min(dir, 7) << 8);
  __syncthreads();
  int cnt = tot_s;
  const float* bse = sl + (size_t)b * CHW_;
  // CE: 8 lanes per entry (lane k = neighbor k)
  for (int base0 = 0; base0 < cnt; base0 += 32) {
    int e = base0 + (tid >> 3), k = tid & 7;
    float ce = 0.f;
    if (e < cnt) {
      int w = list_[e];
      int label = w >> 8, lpos = w & 255;
      int i = i0 + (lpos >> 4), j = j0 + (lpos & 15);
      int pix = i * W_ + j;
      float lzc = logZ[b * HW_ + pix];
      int ic = min(max(i + nx9[k], 0), H_ - 1);
      int jc = min(max(j + ny9[k], 0), W_ - 1);
      int npx = ic * W_ + jc;
      float lzn = logZ[b * HW_ + npx], Sn = S[b * HW_ + npx];
      float dot = 0.f;
      #pragma unroll
      for (int c = 0; c < C_; ++c)
        dot += __expf(bse[c * HW_ + npx] - lzn) * bse[c * HW_ + pix];
      float kv = Sn - dot + lzc;
      float kmax = kv;
      #pragma unroll
      for (int o = 1; o < 8; o <<= 1) kmax = fmaxf(kmax, __shfl_xor(kmax, o));
      float ssum = __expf(kv - kmax);
      #pragma unroll
      for (int o = 1; o < 8; o <<= 1) ssum += __shfl_xor(ssum, o);
      float kll = __shfl(kv, (lane & ~7) | label);
      if (k == 0) ce = kmax + __logf(ssum) - kll;
    }
    acc += ce;
  }
  block_reduce_add_w(acc, out, 4);
}

// ---------------- launch -----------------------------------------------------
extern "C" void kernel_launch(void* const* d_in, const int* in_sizes, int n_in,
                              void* d_out, int out_size, void* d_ws, size_t ws_size,
                              hipStream_t stream) {
  const float* sl  = (const float*)d_in[0];
  const int*   tgt = (const int*)d_in[1];
  float* out = (float*)d_out;

  int*   hist   = (int*)d_ws;               // 257 ints (2 KB region)
  float* logZ   = (float*)d_ws + 512;
  float* S      = logZ + NPIX_;
  float* kl_map = S + NPIX_;
  int*   dist   = (int*)(kl_map + NPIX_);
  int*   R      = dist + NPIX_;

  hipMemsetAsync(d_ws, 0, 2048, stream);
  hipMemsetAsync(d_out, 0, sizeof(float), stream);
  k_front<<<FUSED_BLKS_ + B_ * H_, 320, 0, stream>>>(sl, tgt, R, logZ, S, kl_map, hist, out);
  k_coldt<<<B_ * W_, H_, 0, stream>>>(R, dist);
  k_maskce<<<dim3(W_ / 16, H_ / 16, B_), 256, 0, stream>>>(sl, logZ, S, kl_map, dist, hist, out);
}

// Round 6
// 147.661 us; speedup vs baseline: 1.1046x; 1.1046x over previous
//
#include <hip/hip_runtime.h>
#include <math.h>

#define B_    4
#define C_    19
#define H_    320
#define W_    320
#define HW_   (H_*W_)
#define CHW_  (C_*HW_)
#define NPIX_ (B_*HW_)
#define NEPS_ 256
#define BIGI_ (1<<20)
#define INF_  0x3fffffff
#define IGN_  255
#define FUSED_BLKS_ 640   /* NPIX_/(320 threads * 2 px) */

// Compile-time exact replica of the reference eps chain: e0=1e-5f, e_{k+1}=e_k*1.2f
struct EpsTab { float v[NEPS_]; };
static constexpr EpsTab make_eps() {
  EpsTab t{}; float e = 1e-5f;
  for (int k = 0; k < NEPS_; ++k) { t.v[k] = e; e = e * 1.2f; }
  return t;
}
__device__ __constant__ EpsTab EPS = make_eps();

// ---------------- reduction helper (nw full waves) ---------------------------
__device__ __forceinline__ void block_reduce_add_w(float v, float* out, int nw) {
  #pragma unroll
  for (int o = 32; o > 0; o >>= 1) v += __shfl_down(v, o);
  __shared__ float shr[8];
  int lane = threadIdx.x & 63, wid = threadIdx.x >> 6;
  if (lane == 0) shr[wid] = v;
  __syncthreads();
  if (threadIdx.x == 0) {
    float s = 0.f;
    for (int w = 0; w < nw; ++w) s += shr[w];
    atomicAdd(out, s);
  }
}

__device__ __forceinline__ int eps_bin(float kl, const float* et) {
  // #{k : e_k < kl}, log2 guess + exact correction (identical compares to ref)
  if (!(kl > 1e-5f)) return 0;
  int g = (int)((__log2f(kl) + 16.6096404f) * 3.8017840f);
  g = min(max(g, 0), NEPS_ - 1);
  while (g < NEPS_ && et[g] < kl) ++g;
  while (g > 0 && !(et[g - 1] < kl)) --g;
  return g;
}

// ---------------- K1: fused softmax/kl/hist/nll (blocks 0..639) -------------
//                     row-DT scan             (blocks 640..1919) -------------
__global__ __launch_bounds__(320) void k_front(const float* __restrict__ sl, const int* __restrict__ tgt,
                                               int* __restrict__ R, float* __restrict__ logZ,
                                               float* __restrict__ S, float* __restrict__ kl_map,
                                               int* __restrict__ hist, float* __restrict__ out) {
  int tid = threadIdx.x;
  if (blockIdx.x < FUSED_BLKS_) {
    __shared__ float et[NEPS_];
    __shared__ int sh[257];
    for (int e = tid; e < 257; e += 320) sh[e] = 0;
    for (int e = tid; e < NEPS_; e += 320) et[e] = EPS.v[e];
    __syncthreads();
    int flat0 = blockIdx.x * 640 + tid * 2;
    int b = flat0 / HW_, pix = flat0 - b * HW_;
    int i = pix / W_, j = pix - i * W_;
    const float* base = sl + (size_t)b * CHW_ + pix;
    bool hd = (i < H_ - 1);
    bool hn = (j < W_ - 2);         // right nbr of second pixel
    // pass A: self, keep unnormalized e[c] in registers
    float e0[C_], e1[C_];
    float se0 = 0.f, se1 = 0.f, E0 = 0.f, E1 = 0.f;
    #pragma unroll
    for (int c = 0; c < C_; ++c) {
      float2 xs = *(const float2*)(base + c * HW_);
      float a0 = __expf(xs.x), a1 = __expf(xs.y);
      e0[c] = a0; e1[c] = a1;
      se0 += a0; se1 += a1; E0 += a0 * xs.x; E1 += a1 * xs.y;
    }
    float lz0 = __logf(se0), lz1 = __logf(se1);
    float Sv0 = E0 / se0 - lz0, Sv1 = E1 / se1 - lz1;
    // target nll (scalar reloads hit cache)
    int2 tv = *(const int2*)(tgt + flat0);
    float nll = 0.f;
    if (tv.x != IGN_) nll += lz0 - base[tv.x * HW_];
    if (tv.y != IGN_) nll += lz1 - base[tv.y * HW_ + 1];
    // pass B: down neighbors
    float dd0 = 0.f, dd1 = 0.f, sed0 = 0.f, sed1 = 0.f;
    if (hd) {
      #pragma unroll
      for (int c = 0; c < C_; ++c) {
        float2 xd = *(const float2*)(base + c * HW_ + W_);
        sed0 += __expf(xd.x); sed1 += __expf(xd.y);
        dd0 += e0[c] * xd.x; dd1 += e1[c] * xd.y;
      }
    }
    // pass C: right neighbors. p0's right logits = log(e1[c]) (no loads);
    // p1's right = column j+2 (scalar loads).
    float dr0 = 0.f, dr1 = 0.f, sen = 0.f;
    #pragma unroll
    for (int c = 0; c < C_; ++c) dr0 += e0[c] * __logf(e1[c]);
    if (hn) {
      #pragma unroll
      for (int c = 0; c < C_; ++c) {
        float xr = base[c * HW_ + 2];
        sen += __expf(xr); dr1 += e1[c] * xr;
      }
    }
    float kl0 = (Sv0 - dr0 / se0 + lz1);
    float kl1 = 0.f;
    if (hd) {
      kl0 += Sv0 - dd0 / se0 + __logf(sed0);
      kl1 += Sv1 - dd1 / se1 + __logf(sed1);
    }
    if (hn) kl1 += Sv1 - dr1 / se1 + __logf(sen);
    atomicAdd(&sh[eps_bin(kl0, et)], 1);
    atomicAdd(&sh[eps_bin(kl1, et)], 1);
    *(float2*)(logZ + flat0)   = make_float2(lz0, lz1);
    *(float2*)(S + flat0)      = make_float2(Sv0, Sv1);
    *(float2*)(kl_map + flat0) = make_float2(kl0, kl1);
    __syncthreads();
    for (int e = tid; e < 257; e += 320)
      if (sh[e]) atomicAdd(&hist[e], sh[e]);
    block_reduce_add_w(nll, out, 5);
  } else {
    // ---- row-wise 1D seed distance (Hillis-Steele min scans) ----
    int bid = blockIdx.x - FUSED_BLKS_;
    int b = bid / H_, i = bid % H_, j = tid;
    const int* t = tgt + b * HW_;
    int tij = t[i * W_ + j];
    bool bnd = (tij == IGN_);
    if (i < H_ - 1) bnd |= (t[(i + 1) * W_ + j] != tij);
    if (j < W_ - 1) bnd |= (t[i * W_ + j + 1] != tij);
    int s = bnd ? 0 : BIGI_;
    __shared__ int a[W_], c[W_];
    a[j] = s - j; c[j] = s + j;
    for (int ofs = 1; ofs < W_; ofs <<= 1) {
      __syncthreads();
      int av = (j >= ofs)     ? a[j - ofs] : INF_;
      int cv = (j + ofs < W_) ? c[j + ofs] : INF_;
      __syncthreads();
      a[j] = min(a[j], av); c[j] = min(c[j], cv);
    }
    R[(b * H_ + i) * W_ + j] = min(a[j] + j, c[j] - j);
  }
}

// ---------------- K2: column combine + (block 0) eps selection --------------
__global__ __launch_bounds__(H_) void k_coldt(const int* __restrict__ R, int* __restrict__ dist,
                                              const int* __restrict__ hist, float* __restrict__ eps_sel) {
  int b = blockIdx.x / W_, j = blockIdx.x % W_, tid = threadIdx.x;
  __shared__ int lev[9][H_];
  lev[0][tid] = R[(b * H_ + tid) * W_ + j];
  int Ri = lev[0][tid];
  for (int l = 1; l <= 8; ++l) {
    int half = 1 << (l - 1);
    __syncthreads();
    int other = (tid + half < H_) ? lev[l - 1][tid + half] : INF_;
    lev[l][tid] = min(lev[l - 1][tid], other);
  }
  __syncthreads();
  int i0 = tid;
  auto feas = [&](int dd) -> bool {
    int lo = max(0, i0 - dd), hi = min(H_ - 1, i0 + dd);
    int len = hi - lo + 1;
    int l = 31 - __clz(len);
    int m = min(lev[l][lo], lev[l][hi - (1 << l) + 1]);
    return m <= dd;
  };
  int d;
  int hi = min(Ri, 512);                 // d <= R[i0]
  if (!feas(hi)) d = B_ + 1 + H_ + W_;   // no seed in image
  else {
    int lo = 0;
    while (lo < hi) { int mid = (lo + hi) >> 1; if (feas(mid)) hi = mid; else lo = mid + 1; }
    d = lo;
  }
  dist[(b * H_ + i0) * W_ + j] = d;
  // block 0: eps via suffix scan of hist (bins 1..256)
  if (blockIdx.x == 0) {
    __shared__ int g[256];
    __shared__ int bestk;
    if (tid < 256) g[tid] = hist[tid + 1];
    if (tid == 0) bestk = NEPS_ - 1;
    __syncthreads();
    #pragma unroll
    for (int ofs = 1; ofs < 256; ofs <<= 1) {
      int v = 0;
      if (tid < 256) v = g[tid] + ((tid + ofs < 256) ? g[tid + ofs] : 0);
      __syncthreads();
      if (tid < 256) g[tid] = v;
      __syncthreads();
    }
    if (tid < 256 && g[tid] <= 5120) atomicMin(&bestk, tid);
    __syncthreads();
    if (tid == 0) eps_sel[0] = EPS.v[bestk];
  }
}

// ---------------- K3: mask+direction+dterm + in-block sparse CE -------------
__global__ __launch_bounds__(256) void k_maskce(const float* __restrict__ sl, const float* __restrict__ logZ,
                                                const float* __restrict__ S, const float* __restrict__ kl_map,
                                                const int* __restrict__ dist, const float* __restrict__ eps_sel,
                                                float* __restrict__ out) {
  const int nx9[9] = {1,-1,0,0,-1,1,-1,1,0};
  const int ny9[9] = {0,0,-1,1,1,1,-1,-1,0};
  int tid = threadIdx.x;
  int b = blockIdx.z;
  int i0 = blockIdx.y * 16, j0 = blockIdx.x * 16;
  float eps = eps_sel[0];
  __shared__ float kt[18][19];
  __shared__ int   dt_[18][19];
  for (int e = tid; e < 324; e += 256) {
    int r = e / 18, cc = e - r * 18;
    int gi = i0 - 1 + r, gj = j0 - 1 + cc;
    bool in = (gi >= 0 && gi < H_ && gj >= 0 && gj < W_);
    int gidx = (b * H_ + gi) * W_ + gj;
    kt[r][cc]  = in ? kl_map[gidx] : -1e30f;
    dt_[r][cc] = in ? dist[gidx] : 100000;
  }
  __syncthreads();
  int li = tid >> 4, lj = tid & 15;
  bool mask = false;
  #pragma unroll
  for (int dr = 0; dr < 3; ++dr)
    #pragma unroll
    for (int dc = 0; dc < 3; ++dc)
      mask |= (kt[li + dr][lj + dc] > eps);
  int best = INF_, dir = 0;
  #pragma unroll
  for (int k = 0; k < 9; ++k) {
    int r = dt_[li + 1 + nx9[k]][lj + 1 + ny9[k]];
    if (r < best) { best = r; dir = k; }
  }
  bool valid = mask && (dir != 8);
  float acc = valid ? fminf((float)dt_[li + 1][lj + 1], 20.f) * (1.f / 20.f) : 0.f;
  // compact valid pixels into LDS list
  __shared__ int list_[256];
  __shared__ int woff[4];
  __shared__ int tot_s;
  int lane = tid & 63, wid = tid >> 6;
  unsigned long long vote = __ballot(valid);
  if (lane == 0) woff[wid] = __popcll(vote);
  __syncthreads();
  if (tid == 0) {
    int c0 = woff[0], c1 = woff[1], c2 = woff[2], c3 = woff[3];
    tot_s = c0 + c1 + c2 + c3;
    woff[0] = 0; woff[1] = c0; woff[2] = c0 + c1; woff[3] = c0 + c1 + c2;
  }
  __syncthreads();
  if (valid)
    list_[woff[wid] + __popcll(vote & ((1ULL << lane) - 1ULL))] = tid | (min(dir, 7) << 8);
  __syncthreads();
  int cnt = tot_s;
  const float* bse = sl + (size_t)b * CHW_;
  // CE: 8 lanes per entry (lane k = neighbor k)
  for (int base0 = 0; base0 < cnt; base0 += 32) {
    int e = base0 + (tid >> 3), k = tid & 7;
    float ce = 0.f;
    if (e < cnt) {
      int w = list_[e];
      int label = w >> 8, lpos = w & 255;
      int i = i0 + (lpos >> 4), j = j0 + (lpos & 15);
      int pix = i * W_ + j;
      float lzc = logZ[b * HW_ + pix];
      int ic = min(max(i + nx9[k], 0), H_ - 1);
      int jc = min(max(j + ny9[k], 0), W_ - 1);
      int npx = ic * W_ + jc;
      float lzn = logZ[b * HW_ + npx], Sn = S[b * HW_ + npx];
      float dot = 0.f;
      #pragma unroll
      for (int c = 0; c < C_; ++c)
        dot += __expf(bse[c * HW_ + npx] - lzn) * bse[c * HW_ + pix];
      float kv = Sn - dot + lzc;
      float kmax = kv;
      #pragma unroll
      for (int o = 1; o < 8; o <<= 1) kmax = fmaxf(kmax, __shfl_xor(kmax, o));
      float ssum = __expf(kv - kmax);
      #pragma unroll
      for (int o = 1; o < 8; o <<= 1) ssum += __shfl_xor(ssum, o);
      float kll = __shfl(kv, (lane & ~7) | label);
      if (k == 0) ce = kmax + __logf(ssum) - kll;
    }
    acc += ce;
  }
  block_reduce_add_w(acc, out, 4);
}

// ---------------- launch -----------------------------------------------------
extern "C" void kernel_launch(void* const* d_in, const int* in_sizes, int n_in,
                              void* d_out, int out_size, void* d_ws, size_t ws_size,
                              hipStream_t stream) {
  const float* sl  = (const float*)d_in[0];
  const int*   tgt = (const int*)d_in[1];
  float* out = (float*)d_out;

  int*   hist    = (int*)d_ws;                 // 257 ints
  float* eps_sel = (float*)d_ws + 320;         // inside zeroed 2 KB region
  float* logZ    = (float*)d_ws + 512;
  float* S       = logZ + NPIX_;
  float* kl_map  = S + NPIX_;
  int*   dist    = (int*)(kl_map + NPIX_);
  int*   R       = dist + NPIX_;

  hipMemsetAsync(d_ws, 0, 2048, stream);
  hipMemsetAsync(d_out, 0, sizeof(float), stream);
  k_front<<<FUSED_BLKS_ + B_ * H_, 320, 0, stream>>>(sl, tgt, R, logZ, S, kl_map, hist, out);
  k_coldt<<<B_ * W_, H_, 0, stream>>>(R, dist, hist, eps_sel);
  k_maskce<<<dim3(W_ / 16, H_ / 16, B_), 256, 0, stream>>>(sl, logZ, S, kl_map, dist, eps_sel, out);
}